// Round 5
// baseline (1835.344 us; speedup 1.0000x reference)
//
#include <hip/hip_runtime.h>
#include <hip/hip_bf16.h>
#include <hip/hip_fp16.h>

#define NDIM 100
#define HDIM 16
#define CDIM 20

#define BSH2   10                 // 1024 nodes per bucket
#define BMASK2 ((1 << BSH2) - 1)
#define NB2MAX 768                // supports N <= 786432 (3*256 for LDS scan)
#define CH2    16384              // edges per scatter_sort block
#define ACC_PITCH 17              // 1024x16 acc padded -> bank-conflict-free

// fp16 pack/unpack helpers (tables stored fp16, accumulation fp32)
__device__ inline float2 h2f2(unsigned u) {
    __half2 h = *reinterpret_cast<__half2*>(&u);
    return __half22float2(h);
}
__device__ inline unsigned f2h2(float a, float b) {
    __half2 h = __floats2half2_rn(a, b);
    return *reinterpret_cast<unsigned*>(&h);
}

// ---------------- pass A: bucket histogram -> bcnt[b] ----------------

__global__ __launch_bounds__(256) void histA(const int* __restrict__ dst,
                                             int* __restrict__ bcnt,
                                             int E, int NB2) {
    __shared__ int lh[NB2MAX];
    for (int t = threadIdx.x; t < NB2MAX; t += 256) lh[t] = 0;
    __syncthreads();

    int base = blockIdx.x * 8192;
    int endv = min(base + 8192, E);
    for (int e = base + threadIdx.x; e < endv; e += 256)
        atomicAdd(&lh[dst[e] >> BSH2], 1);
    __syncthreads();

    for (int t = threadIdx.x; t < NB2; t += 256) {
        int v = lh[t];
        if (v) atomicAdd(&bcnt[t], v);
    }
}

// ---- exclusive scan of bcnt in place (nb <= 2048), 1 block; also seeds gcur ----

__global__ __launch_bounds__(256) void scan_k2(int* __restrict__ bsum,
                                               int* __restrict__ gcur, int nb) {
    __shared__ int part[256];
    int t = threadIdx.x;
    int base = t * 8;
    int loc[8];
    int s = 0;
#pragma unroll
    for (int k = 0; k < 8; ++k) {
        int idx = base + k;
        loc[k] = (idx < nb) ? bsum[idx] : 0;
        s += loc[k];
    }
    part[t] = s;
    __syncthreads();
    for (int off = 1; off < 256; off <<= 1) {
        int add = (t >= off) ? part[t - off] : 0;
        __syncthreads();
        part[t] += add;
        __syncthreads();
    }
    int run = (t > 0) ? part[t - 1] : 0;
#pragma unroll
    for (int k = 0; k < 8; ++k) {
        int idx = base + k;
        if (idx < nb) { bsum[idx] = run; gcur[idx] = run; }
        run += loc[k];
    }
}

// ---------------- pass B: block-local counting sort in LDS + full-line copy-out ----

__global__ __launch_bounds__(256) void scatter_sort(const int* __restrict__ src,
                                                    const int* __restrict__ dst,
                                                    int* __restrict__ gcur,
                                                    unsigned* __restrict__ tmp,
                                                    int E, int NB2) {
    __shared__ unsigned lbuf[CH2];
    __shared__ int lcnt[NB2MAX];   // counts, later local cursors (-> ends)
    __shared__ int lst[NB2MAX];    // local exclusive starts
    __shared__ int gb[NB2MAX];     // global run bases
    __shared__ int part[256];
    const int t = threadIdx.x;

    for (int i = t; i < NB2MAX; i += 256) lcnt[i] = 0;
    __syncthreads();

    int base = blockIdx.x * CH2;
    int endv = min(base + CH2, E);
    for (int e = base + t; e < endv; e += 256)
        atomicAdd(&lcnt[dst[e] >> BSH2], 1);
    __syncthreads();

    int c0 = lcnt[3 * t], c1 = lcnt[3 * t + 1], c2 = lcnt[3 * t + 2];
    part[t] = c0 + c1 + c2;
    __syncthreads();
    for (int off = 1; off < 256; off <<= 1) {
        int add = (t >= off) ? part[t - off] : 0;
        __syncthreads();
        part[t] += add;
        __syncthreads();
    }
    int ex = (t > 0) ? part[t - 1] : 0;
    lst[3 * t]     = ex;
    lst[3 * t + 1] = ex + c0;
    lst[3 * t + 2] = ex + c0 + c1;

    for (int i = t; i < NB2; i += 256)
        gb[i] = atomicAdd(&gcur[i], lcnt[i]);
    __syncthreads();

    for (int i = t; i < NB2MAX; i += 256) lcnt[i] = lst[i];
    __syncthreads();

    for (int e = base + t; e < endv; e += 256) {
        int d = dst[e];
        int b = d >> BSH2;
        int pos = atomicAdd(&lcnt[b], 1);
        lbuf[pos] = ((unsigned)src[e] << BSH2) | (unsigned)(d & BMASK2);
    }
    __syncthreads();

    // copy-out: 16-lane groups, 16 buckets concurrently (runs ~33 entries)
    int grp = t >> 4, lane = t & 15;
    for (int b = grp; b < NB2; b += 16) {
        int s0 = lst[b], g0 = gb[b];
        int len = lcnt[b] - s0;
        for (int k = lane; k < len; k += 16)
            tmp[(size_t)g0 + k] = lbuf[s0 + k];
    }
}

// ---------------- degB: per-bucket degree histogram -> dinv ----------------

__global__ __launch_bounds__(256) void degB(const unsigned* __restrict__ tmp,
                                            const int* __restrict__ B0,
                                            float* __restrict__ dinv,
                                            int N, int E, int NB2) {
    __shared__ int lh[1024];
    int b = blockIdx.x, t = threadIdx.x;
    for (int i = t; i < 1024; i += 256) lh[i] = 0;
    __syncthreads();

    int lo = B0[b];
    int hi = (b + 1 < NB2) ? B0[b + 1] : E;
    for (int i = lo + t; i < hi; i += 256)
        atomicAdd(&lh[tmp[i] & BMASK2], 1);
    __syncthreads();

    int base_node = b << BSH2;
    for (int i = t; i < 1024; i += 256) {
        int node = base_node + i;
        if (node < N) dinv[node] = rsqrtf((float)(lh[i] + 1));  // +1 = self-loop
    }
}

// ---------------- xw1h = fp16( dinv[n] * (x @ W1) )  ([N,100] @ [100,16]) ----------------

__global__ __launch_bounds__(256) void xw1_kernel(const float* __restrict__ x,
                                                  const float* __restrict__ W1,
                                                  const float* __restrict__ dinv,
                                                  __half* __restrict__ xw1h, int N) {
    __shared__ float Ws[NDIM * HDIM];  // [k][j]
    for (int t = threadIdx.x; t < NDIM * HDIM; t += 256) Ws[t] = W1[t];
    __syncthreads();

    const int ln = threadIdx.x >> 2;
    const int q  = threadIdx.x & 3;
    const int node = blockIdx.x * 64 + ln;
    if (node >= N) return;

    const float4* xr  = reinterpret_cast<const float4*>(x + (size_t)node * NDIM);
    const float4* Ws4 = reinterpret_cast<const float4*>(Ws);

    float4 acc = make_float4(0.f, 0.f, 0.f, 0.f);
#pragma unroll
    for (int kk = 0; kk < NDIM / 4; ++kk) {
        float4 xv = xr[kk];
        float xs[4] = {xv.x, xv.y, xv.z, xv.w};
#pragma unroll
        for (int c = 0; c < 4; ++c) {
            float4 w = Ws4[(kk * 4 + c) * 4 + q];
            acc.x += xs[c] * w.x;
            acc.y += xs[c] * w.y;
            acc.z += xs[c] * w.z;
            acc.w += xs[c] * w.w;
        }
    }
    float dn = dinv[node];
    uint2 o;
    o.x = f2h2(dn * acc.x, dn * acc.y);
    o.y = f2h2(dn * acc.z, dn * acc.w);
    reinterpret_cast<uint2*>(xw1h)[(size_t)node * 4 + q] = o;
}

// ---------------- gatherE1: edge-parallel layer-1 aggregate in LDS ----------------
// One block per bucket. acc[1024][16] fp32 (pitch 17). Stream tmp run,
// ds_add_f32 into acc, epilogue -> hsh = fp16(dinv * relu(dn*acc + b1)).

__global__ __launch_bounds__(512) void gatherE1(const unsigned* __restrict__ tmp,
                                                const int* __restrict__ B0,
                                                const float* __restrict__ dinv,
                                                const __half* __restrict__ xw1h,
                                                const float* __restrict__ b1,
                                                __half* __restrict__ hsh,
                                                int N, int E, int NB2) {
    __shared__ float acc[1024 * ACC_PITCH];  // 69632 B
    const int b = blockIdx.x, t = threadIdx.x;
    const int g = t >> 2, f4 = t & 3;        // 128 groups of 4 lanes
    const int base_node = b << BSH2;
    const uint2* T = reinterpret_cast<const uint2*>(xw1h);

    // init: self term (pre-scaled rows), 8 nodes per group
#pragma unroll
    for (int r = 0; r < 8; ++r) {
        int nl = g + r * 128;
        int node = base_node + nl;
        float4 v = make_float4(0.f, 0.f, 0.f, 0.f);
        if (node < N) {
            uint2 u = T[(size_t)node * 4 + f4];
            float2 p = h2f2(u.x), q = h2f2(u.y);
            v = make_float4(p.x, p.y, q.x, q.y);
        }
        float* row = &acc[nl * ACC_PITCH + f4 * 4];
        row[0] = v.x; row[1] = v.y; row[2] = v.z; row[3] = v.w;
    }
    __syncthreads();

    int lo = B0[b];
    int hi = (b + 1 < NB2) ? B0[b + 1] : E;

    int i = lo + g;
    for (; i + 128 < hi; i += 256) {
        unsigned v0 = tmp[i], v1 = tmp[i + 128];
        int s0 = v0 >> BSH2, n0 = v0 & BMASK2;
        int s1 = v1 >> BSH2, n1 = v1 & BMASK2;
        uint2 u0 = T[(size_t)s0 * 4 + f4];
        uint2 u1 = T[(size_t)s1 * 4 + f4];
        float2 p0 = h2f2(u0.x), q0 = h2f2(u0.y);
        float2 p1 = h2f2(u1.x), q1 = h2f2(u1.y);
        float* r0 = &acc[n0 * ACC_PITCH + f4 * 4];
        atomicAdd(&r0[0], p0.x); atomicAdd(&r0[1], p0.y);
        atomicAdd(&r0[2], q0.x); atomicAdd(&r0[3], q0.y);
        float* r1 = &acc[n1 * ACC_PITCH + f4 * 4];
        atomicAdd(&r1[0], p1.x); atomicAdd(&r1[1], p1.y);
        atomicAdd(&r1[2], q1.x); atomicAdd(&r1[3], q1.y);
    }
    for (; i < hi; i += 128) {
        unsigned v = tmp[i];
        int s = v >> BSH2, nl = v & BMASK2;
        uint2 u = T[(size_t)s * 4 + f4];
        float2 p = h2f2(u.x), q = h2f2(u.y);
        float* row = &acc[nl * ACC_PITCH + f4 * 4];
        atomicAdd(&row[0], p.x); atomicAdd(&row[1], p.y);
        atomicAdd(&row[2], q.x); atomicAdd(&row[3], q.y);
    }
    __syncthreads();

    // epilogue: hsh = fp16( dn * relu(dn*acc + b1) )
    float4 bv = reinterpret_cast<const float4*>(b1)[f4];
#pragma unroll
    for (int r = 0; r < 8; ++r) {
        int nl = g + r * 128;
        int node = base_node + nl;
        if (node >= N) continue;
        float dn = dinv[node];
        float* row = &acc[nl * ACC_PITCH + f4 * 4];
        float hx = dn * fmaxf(dn * row[0] + bv.x, 0.f);
        float hy = dn * fmaxf(dn * row[1] + bv.y, 0.f);
        float hz = dn * fmaxf(dn * row[2] + bv.z, 0.f);
        float hw = dn * fmaxf(dn * row[3] + bv.w, 0.f);
        uint2 o;
        o.x = f2h2(hx, hy);
        o.y = f2h2(hz, hw);
        reinterpret_cast<uint2*>(hsh)[(size_t)node * 4 + f4] = o;
    }
}

// ---------------- gatherE2: edge-parallel layer-2 + fused W2 matmul + log_softmax ----

__global__ __launch_bounds__(512) void gatherE2(const unsigned* __restrict__ tmp,
                                                const int* __restrict__ B0,
                                                const float* __restrict__ dinv,
                                                const __half* __restrict__ hsh,
                                                const float* __restrict__ W2,
                                                const float* __restrict__ b2,
                                                float* __restrict__ out,
                                                int N, int E, int NB2) {
    __shared__ float acc[1024 * ACC_PITCH];  // 69632 B
    __shared__ float W2s[HDIM * CDIM];       // [k][j], original layout
    __shared__ float b2s[CDIM];
    const int b = blockIdx.x, t = threadIdx.x;
    const int g = t >> 2, f4 = t & 3;
    const int base_node = b << BSH2;
    const uint2* T = reinterpret_cast<const uint2*>(hsh);

    for (int i = t; i < HDIM * CDIM; i += 512) W2s[i] = W2[i];
    if (t < CDIM) b2s[t] = b2[t];

    // init: self term
#pragma unroll
    for (int r = 0; r < 8; ++r) {
        int nl = g + r * 128;
        int node = base_node + nl;
        float4 v = make_float4(0.f, 0.f, 0.f, 0.f);
        if (node < N) {
            uint2 u = T[(size_t)node * 4 + f4];
            float2 p = h2f2(u.x), q = h2f2(u.y);
            v = make_float4(p.x, p.y, q.x, q.y);
        }
        float* row = &acc[nl * ACC_PITCH + f4 * 4];
        row[0] = v.x; row[1] = v.y; row[2] = v.z; row[3] = v.w;
    }
    __syncthreads();

    int lo = B0[b];
    int hi = (b + 1 < NB2) ? B0[b + 1] : E;

    int i = lo + g;
    for (; i + 128 < hi; i += 256) {
        unsigned v0 = tmp[i], v1 = tmp[i + 128];
        int s0 = v0 >> BSH2, n0 = v0 & BMASK2;
        int s1 = v1 >> BSH2, n1 = v1 & BMASK2;
        uint2 u0 = T[(size_t)s0 * 4 + f4];
        uint2 u1 = T[(size_t)s1 * 4 + f4];
        float2 p0 = h2f2(u0.x), q0 = h2f2(u0.y);
        float2 p1 = h2f2(u1.x), q1 = h2f2(u1.y);
        float* r0 = &acc[n0 * ACC_PITCH + f4 * 4];
        atomicAdd(&r0[0], p0.x); atomicAdd(&r0[1], p0.y);
        atomicAdd(&r0[2], q0.x); atomicAdd(&r0[3], q0.y);
        float* r1 = &acc[n1 * ACC_PITCH + f4 * 4];
        atomicAdd(&r1[0], p1.x); atomicAdd(&r1[1], p1.y);
        atomicAdd(&r1[2], q1.x); atomicAdd(&r1[3], q1.y);
    }
    for (; i < hi; i += 128) {
        unsigned v = tmp[i];
        int s = v >> BSH2, nl = v & BMASK2;
        uint2 u = T[(size_t)s * 4 + f4];
        float2 p = h2f2(u.x), q = h2f2(u.y);
        float* row = &acc[nl * ACC_PITCH + f4 * 4];
        atomicAdd(&row[0], p.x); atomicAdd(&row[1], p.y);
        atomicAdd(&row[2], q.x); atomicAdd(&row[3], q.y);
    }
    __syncthreads();

    // epilogue: per-node 16x20 matmul + log_softmax, 2 nodes/thread
#pragma unroll
    for (int r = 0; r < 2; ++r) {
        int nl = t + r * 512;
        int node = base_node + nl;
        if (node >= N) continue;
        float dn = dinv[node];
        float a[HDIM];
        float* row = &acc[nl * ACC_PITCH];
#pragma unroll
        for (int k = 0; k < HDIM; ++k) a[k] = dn * row[k];
        float o[CDIM];
#pragma unroll
        for (int j = 0; j < CDIM; ++j) o[j] = b2s[j];
#pragma unroll
        for (int k = 0; k < HDIM; ++k) {
            float ak = a[k];
#pragma unroll
            for (int j = 0; j < CDIM; ++j) o[j] += ak * W2s[k * CDIM + j];
        }
        float m = o[0];
#pragma unroll
        for (int j = 1; j < CDIM; ++j) m = fmaxf(m, o[j]);
        float s = 0.f;
#pragma unroll
        for (int j = 0; j < CDIM; ++j) s += __expf(o[j] - m);
        float l = m + __logf(s);
        float4* out4 = reinterpret_cast<float4*>(out + (size_t)node * CDIM);
#pragma unroll
        for (int c = 0; c < CDIM / 4; ++c)
            out4[c] = make_float4(o[4 * c + 0] - l, o[4 * c + 1] - l,
                                  o[4 * c + 2] - l, o[4 * c + 3] - l);
    }
}

// ---------------- launch ----------------

extern "C" void kernel_launch(void* const* d_in, const int* in_sizes, int n_in,
                              void* d_out, int out_size, void* d_ws, size_t ws_size,
                              hipStream_t stream) {
    const float* x  = (const float*)d_in[0];
    const int* edge = (const int*)d_in[1];   // [2, E] int32
    const float* W1 = (const float*)d_in[2];
    const float* b1 = (const float*)d_in[3];
    const float* W2 = (const float*)d_in[4];
    const float* b2 = (const float*)d_in[5];
    float* out = (float*)d_out;

    const int N = in_sizes[0] / NDIM;   // 500000
    const int E = in_sizes[1] / 2;      // 8000000
    const int* src = edge;
    const int* dst = edge + E;

    const int tb = 256;
    const int NB2 = (N + BMASK2) >> BSH2;       // 489 coarse buckets

    char* ws = (char*)d_ws;
    size_t off = 0;
    float*    dinv = (float*)(ws + off);    off += (size_t)N * 4;
    __half*   xw1h = (__half*)(ws + off);   off += (size_t)N * HDIM * 2;
    __half*   hsh  = (__half*)(ws + off);   off += (size_t)N * HDIM * 2;
    unsigned* tmp  = (unsigned*)(ws + off); off += (size_t)E * 4;
    int*      bcnt = (int*)(ws + off);      off += (size_t)NB2MAX * 4;
    int*      gcur = (int*)(ws + off);      off += (size_t)NB2MAX * 4;

    // ---- CSR-lite build: coarse sort only (no per-node sort needed) ----
    hipMemsetAsync(bcnt, 0, (size_t)NB2 * 4, stream);
    histA<<<(E + 8191) / 8192, tb, 0, stream>>>(dst, bcnt, E, NB2);
    scan_k2<<<1, tb, 0, stream>>>(bcnt, gcur, NB2);   // bcnt -> B0, seeds gcur
    scatter_sort<<<(E + CH2 - 1) / CH2, tb, 0, stream>>>(src, dst, gcur, tmp, E, NB2);

    // degrees -> dinv (per-bucket LDS histogram over tmp)
    degB<<<NB2, tb, 0, stream>>>(tmp, bcnt, dinv, N, E, NB2);

    // dense matmul xw1h = fp16(dinv * (x @ W1))
    xw1_kernel<<<(N + 63) / 64, tb, 0, stream>>>(x, W1, dinv, xw1h, N);

    // layer 1: edge-parallel aggregate + relu epilogue -> hsh
    gatherE1<<<NB2, 512, 0, stream>>>(tmp, bcnt, dinv, xw1h, b1, hsh, N, E, NB2);

    // layer 2: edge-parallel aggregate + fused W2 matmul + log_softmax -> out
    gatherE2<<<NB2, 512, 0, stream>>>(tmp, bcnt, dinv, hsh, W2, b2, out, N, E, NB2);
}

// Round 7
// 866.313 us; speedup vs baseline: 2.1186x; 2.1186x over previous
//
#include <hip/hip_runtime.h>
#include <hip/hip_bf16.h>
#include <hip/hip_fp16.h>

#define NDIM 100
#define HDIM 16
#define CDIM 20

#define BSH2   10                 // 1024 nodes per bucket
#define BMASK2 ((1 << BSH2) - 1)
#define NB2MAX 768                // supports N <= 786432 (3*256 for LDS scan)
#define CH2    16384              // edges per scatter_sort block
#define LBUF_CAP 18432            // binC LDS staging capacity

// fp16 pack/unpack helpers (tables stored fp16, accumulation fp32)
__device__ inline float2 h2f2(unsigned u) {
    __half2 h = *reinterpret_cast<__half2*>(&u);
    return __half22float2(h);
}
__device__ inline unsigned f2h2(float a, float b) {
    __half2 h = __floats2half2_rn(a, b);
    return *reinterpret_cast<unsigned*>(&h);
}

// non-temporal load helpers (streaming data: don't pollute L2; keep hot tables resident)
// NOTE: __builtin_nontemporal_* requires scalar or clang-native vector types,
// not HIP_vector_type structs -> go through ext_vector_type(4) float.
typedef float fvec4 __attribute__((ext_vector_type(4)));

__device__ inline int ntl_i(const int* p) { return __builtin_nontemporal_load(p); }
__device__ inline float4 ntl_f4(const float4* p) {
    fvec4 u = __builtin_nontemporal_load(reinterpret_cast<const fvec4*>(p));
    return make_float4(u.x, u.y, u.z, u.w);
}
__device__ inline void nts_f4(float4* p, float4 v) {
    fvec4 u = {v.x, v.y, v.z, v.w};
    __builtin_nontemporal_store(u, reinterpret_cast<fvec4*>(p));
}

// ---------------- pass A: bucket histogram -> bcnt[b] ----------------

__global__ __launch_bounds__(256) void histA(const int* __restrict__ dst,
                                             int* __restrict__ bcnt,
                                             int E, int NB2) {
    __shared__ int lh[NB2MAX];
    for (int t = threadIdx.x; t < NB2MAX; t += 256) lh[t] = 0;
    __syncthreads();

    int base = blockIdx.x * 8192;
    int endv = min(base + 8192, E);
    for (int e = base + threadIdx.x; e < endv; e += 256)
        atomicAdd(&lh[ntl_i(&dst[e]) >> BSH2], 1);
    __syncthreads();

    for (int t = threadIdx.x; t < NB2; t += 256) {
        int v = lh[t];
        if (v) atomicAdd(&bcnt[t], v);
    }
}

// ---- exclusive scan of bcnt in place (nb <= 2048), 1 block; also seeds gcur ----

__global__ __launch_bounds__(256) void scan_k2(int* __restrict__ bsum,
                                               int* __restrict__ gcur, int nb) {
    __shared__ int part[256];
    int t = threadIdx.x;
    int base = t * 8;
    int loc[8];
    int s = 0;
#pragma unroll
    for (int k = 0; k < 8; ++k) {
        int idx = base + k;
        loc[k] = (idx < nb) ? bsum[idx] : 0;
        s += loc[k];
    }
    part[t] = s;
    __syncthreads();
    for (int off = 1; off < 256; off <<= 1) {
        int add = (t >= off) ? part[t - off] : 0;
        __syncthreads();
        part[t] += add;
        __syncthreads();
    }
    int run = (t > 0) ? part[t - 1] : 0;
#pragma unroll
    for (int k = 0; k < 8; ++k) {
        int idx = base + k;
        if (idx < nb) { bsum[idx] = run; gcur[idx] = run; }
        run += loc[k];
    }
}

// ---------------- pass B: block-local counting sort in LDS + full-line copy-out ----

__global__ __launch_bounds__(256) void scatter_sort(const int* __restrict__ src,
                                                    const int* __restrict__ dst,
                                                    int* __restrict__ gcur,
                                                    unsigned* __restrict__ tmp,
                                                    int E, int NB2) {
    __shared__ unsigned lbuf[CH2];
    __shared__ int lcnt[NB2MAX];   // counts, later local cursors (-> ends)
    __shared__ int lst[NB2MAX];    // local exclusive starts
    __shared__ int gb[NB2MAX];     // global run bases
    __shared__ int part[256];
    const int t = threadIdx.x;

    for (int i = t; i < NB2MAX; i += 256) lcnt[i] = 0;
    __syncthreads();

    int base = blockIdx.x * CH2;
    int endv = min(base + CH2, E);
    for (int e = base + t; e < endv; e += 256)
        atomicAdd(&lcnt[ntl_i(&dst[e]) >> BSH2], 1);
    __syncthreads();

    int c0 = lcnt[3 * t], c1 = lcnt[3 * t + 1], c2 = lcnt[3 * t + 2];
    part[t] = c0 + c1 + c2;
    __syncthreads();
    for (int off = 1; off < 256; off <<= 1) {
        int add = (t >= off) ? part[t - off] : 0;
        __syncthreads();
        part[t] += add;
        __syncthreads();
    }
    int ex = (t > 0) ? part[t - 1] : 0;
    lst[3 * t]     = ex;
    lst[3 * t + 1] = ex + c0;
    lst[3 * t + 2] = ex + c0 + c1;

    for (int i = t; i < NB2; i += 256)
        gb[i] = atomicAdd(&gcur[i], lcnt[i]);
    __syncthreads();

    for (int i = t; i < NB2MAX; i += 256) lcnt[i] = lst[i];
    __syncthreads();

    for (int e = base + t; e < endv; e += 256) {
        int d = ntl_i(&dst[e]);
        int b = d >> BSH2;
        int pos = atomicAdd(&lcnt[b], 1);
        lbuf[pos] = ((unsigned)ntl_i(&src[e]) << BSH2) | (unsigned)(d & BMASK2);
    }
    __syncthreads();

    // copy-out: 16-lane groups, 16 buckets concurrently (runs ~33 entries)
    int grp = t >> 4, lane = t & 15;
    for (int b = grp; b < NB2; b += 16) {
        int s0 = lst[b], g0 = gb[b];
        int len = lcnt[b] - s0;
        for (int k = lane; k < len; k += 16)
            tmp[(size_t)g0 + k] = lbuf[s0 + k];
    }
}

// ---------------- pass C: one block per bucket -> deg, cursor(end), esrc ----------------

__global__ __launch_bounds__(256) void binC(const unsigned* __restrict__ tmp,
                                            const int* __restrict__ B0,
                                            int* __restrict__ deg,
                                            int* __restrict__ cursor,
                                            int* __restrict__ esrc,
                                            int N, int E, int NB2) {
    __shared__ int lbuf[LBUF_CAP];
    __shared__ int lh[1024];
    __shared__ int part[256];
    int b = blockIdx.x, t = threadIdx.x;

    for (int i = t; i < 1024; i += 256) lh[i] = 0;
    __syncthreads();

    int lo = B0[b];
    int hi = (b + 1 < NB2) ? B0[b + 1] : E;

    for (int i = lo + t; i < hi; i += 256)
        atomicAdd(&lh[tmp[i] & BMASK2], 1);
    __syncthreads();

    int c[4];
    int s = 0;
#pragma unroll
    for (int k = 0; k < 4; ++k) { c[k] = lh[4 * t + k]; s += c[k]; }
    part[t] = s;
    __syncthreads();
    for (int off = 1; off < 256; off <<= 1) {
        int add = (t >= off) ? part[t - off] : 0;
        __syncthreads();
        part[t] += add;
        __syncthreads();
    }
    int run = (t > 0) ? part[t - 1] : 0;
    bool fits = (hi - lo) <= LBUF_CAP;

#pragma unroll
    for (int k = 0; k < 4; ++k) {
        int node = (b << BSH2) + 4 * t + k;
        int st = run;
        run += c[k];
        if (node < N) {
            deg[node]    = c[k];
            cursor[node] = lo + run;
        }
        lh[4 * t + k] = st;
    }
    __syncthreads();

    if (fits) {
        for (int i = lo + t; i < hi; i += 256) {
            unsigned v = tmp[i];
            int pos = atomicAdd(&lh[v & BMASK2], 1);
            lbuf[pos] = (int)(v >> BSH2);
        }
        __syncthreads();
        for (int i = lo + t; i < hi; i += 256)
            esrc[i] = lbuf[i - lo];
    } else {
        for (int i = lo + t; i < hi; i += 256) {
            unsigned v = tmp[i];
            int pos = atomicAdd(&lh[v & BMASK2], 1);
            esrc[(size_t)lo + pos] = (int)(v >> BSH2);
        }
    }
}

// ---------------- dinv ----------------

__global__ __launch_bounds__(256) void dinv_kernel(const int* __restrict__ deg,
                                                   float* __restrict__ dinv, int N) {
    int i = blockIdx.x * blockDim.x + threadIdx.x;
    if (i < N) dinv[i] = rsqrtf((float)(deg[i] + 1));  // +1 = self-loop
}

// ---------------- xw1h = fp16( dinv[n] * (x @ W1) )  ([N,100] @ [100,16]) ----------------

__global__ __launch_bounds__(256) void xw1_kernel(const float* __restrict__ x,
                                                  const float* __restrict__ W1,
                                                  const float* __restrict__ dinv,
                                                  __half* __restrict__ xw1h, int N) {
    __shared__ float Ws[NDIM * HDIM];  // [k][j]
    for (int t = threadIdx.x; t < NDIM * HDIM; t += 256) Ws[t] = W1[t];
    __syncthreads();

    const int ln = threadIdx.x >> 2;
    const int q  = threadIdx.x & 3;
    const int node = blockIdx.x * 64 + ln;
    if (node >= N) return;

    const float4* xr  = reinterpret_cast<const float4*>(x + (size_t)node * NDIM);
    const float4* Ws4 = reinterpret_cast<const float4*>(Ws);

    float4 acc = make_float4(0.f, 0.f, 0.f, 0.f);
#pragma unroll
    for (int kk = 0; kk < NDIM / 4; ++kk) {
        float4 xv = ntl_f4(&xr[kk]);
        float xs[4] = {xv.x, xv.y, xv.z, xv.w};
#pragma unroll
        for (int c = 0; c < 4; ++c) {
            float4 w = Ws4[(kk * 4 + c) * 4 + q];
            acc.x += xs[c] * w.x;
            acc.y += xs[c] * w.y;
            acc.z += xs[c] * w.z;
            acc.w += xs[c] * w.w;
        }
    }
    float dn = dinv[node];
    uint2 o;
    o.x = f2h2(dn * acc.x, dn * acc.y);
    o.y = f2h2(dn * acc.z, dn * acc.w);
    reinterpret_cast<uint2*>(xw1h)[(size_t)node * 4 + q] = o;
}

// ---------------- layer-1 gather: hsh = fp16(dinv * relu(dn*(sum + self) + b1)) ----
// 4 lanes per node, 8B (half4) per lane; 64 nodes per 256-thread block.

__global__ __launch_bounds__(256) void gather1(const int* __restrict__ esrc,
                                               const int* __restrict__ cursor,
                                               const int* __restrict__ deg,
                                               const float* __restrict__ dinv,
                                               const __half* __restrict__ xw1h,
                                               const float* __restrict__ b1,
                                               __half* __restrict__ hsh, int N) {
    int g  = threadIdx.x >> 2;
    int f4 = threadIdx.x & 3;
    int n  = blockIdx.x * 64 + g;
    if (n >= N) return;

    int end   = cursor[n];
    int start = end - deg[n];
    float dn  = dinv[n];

    const uint2* T = reinterpret_cast<const uint2*>(xw1h);
    uint2 sv = T[(size_t)n * 4 + f4];
    float2 s01 = h2f2(sv.x), s23 = h2f2(sv.y);
    float4 a0 = make_float4(s01.x, s01.y, s23.x, s23.y);  // self term
    float4 a1 = make_float4(0.f, 0.f, 0.f, 0.f);

    int j = start;
    for (; j + 3 < end; j += 4) {
        int i0 = ntl_i(&esrc[j + 0]), i1 = ntl_i(&esrc[j + 1]);
        int i2 = ntl_i(&esrc[j + 2]), i3 = ntl_i(&esrc[j + 3]);
        uint2 v0 = T[(size_t)i0 * 4 + f4];
        uint2 v1 = T[(size_t)i1 * 4 + f4];
        uint2 v2 = T[(size_t)i2 * 4 + f4];
        uint2 v3 = T[(size_t)i3 * 4 + f4];
        float2 p, q;
        p = h2f2(v0.x); q = h2f2(v0.y);
        a0.x += p.x; a0.y += p.y; a0.z += q.x; a0.w += q.y;
        p = h2f2(v1.x); q = h2f2(v1.y);
        a1.x += p.x; a1.y += p.y; a1.z += q.x; a1.w += q.y;
        p = h2f2(v2.x); q = h2f2(v2.y);
        a0.x += p.x; a0.y += p.y; a0.z += q.x; a0.w += q.y;
        p = h2f2(v3.x); q = h2f2(v3.y);
        a1.x += p.x; a1.y += p.y; a1.z += q.x; a1.w += q.y;
    }
    for (; j < end; ++j) {
        int s = ntl_i(&esrc[j]);
        uint2 v = T[(size_t)s * 4 + f4];
        float2 p = h2f2(v.x), q = h2f2(v.y);
        a0.x += p.x; a0.y += p.y; a0.z += q.x; a0.w += q.y;
    }
    float4 acc = make_float4(a0.x + a1.x, a0.y + a1.y, a0.z + a1.z, a0.w + a1.w);
    float4 bv = reinterpret_cast<const float4*>(b1)[f4];
    float hx = dn * fmaxf(dn * acc.x + bv.x, 0.f);
    float hy = dn * fmaxf(dn * acc.y + bv.y, 0.f);
    float hz = dn * fmaxf(dn * acc.z + bv.z, 0.f);
    float hw = dn * fmaxf(dn * acc.w + bv.w, 0.f);
    uint2 o;
    o.x = f2h2(hx, hy);
    o.y = f2h2(hz, hw);
    reinterpret_cast<uint2*>(hsh)[(size_t)n * 4 + f4] = o;
}

// ---------------- layer-2 gather + fused W2 matmul + log_softmax -> out ----------------
// Same 4-lane gather; epilogue stages 64x16 acc in LDS, threads 0..63 finish.

__global__ __launch_bounds__(256) void gather2(const int* __restrict__ esrc,
                                               const int* __restrict__ cursor,
                                               const int* __restrict__ deg,
                                               const float* __restrict__ dinv,
                                               const __half* __restrict__ hsh,
                                               const float* __restrict__ W2,
                                               const float* __restrict__ b2,
                                               float* __restrict__ out, int N) {
    __shared__ float sacc[64 * 17];
    __shared__ float W2s[HDIM * CDIM];   // [k][j] original layout
    __shared__ float b2s[CDIM];
    const int t  = threadIdx.x;
    const int g  = t >> 2;
    const int f4 = t & 3;
    const int n  = blockIdx.x * 64 + g;
    const bool active = (n < N);

    for (int i = t; i < HDIM * CDIM; i += 256) W2s[i] = W2[i];
    if (t < CDIM) b2s[t] = b2[t];

    const uint2* T = reinterpret_cast<const uint2*>(hsh);
    float4 a0 = make_float4(0.f, 0.f, 0.f, 0.f);
    float4 a1 = make_float4(0.f, 0.f, 0.f, 0.f);
    float dn = 0.f;
    int start = 0, end = 0;
    if (active) {
        end   = cursor[n];
        start = end - deg[n];
        dn    = dinv[n];
        uint2 sv = T[(size_t)n * 4 + f4];
        float2 s01 = h2f2(sv.x), s23 = h2f2(sv.y);
        a0 = make_float4(s01.x, s01.y, s23.x, s23.y);  // self term
    }

    int j = start;
    for (; j + 3 < end; j += 4) {
        int i0 = ntl_i(&esrc[j + 0]), i1 = ntl_i(&esrc[j + 1]);
        int i2 = ntl_i(&esrc[j + 2]), i3 = ntl_i(&esrc[j + 3]);
        uint2 v0 = T[(size_t)i0 * 4 + f4];
        uint2 v1 = T[(size_t)i1 * 4 + f4];
        uint2 v2 = T[(size_t)i2 * 4 + f4];
        uint2 v3 = T[(size_t)i3 * 4 + f4];
        float2 p, q;
        p = h2f2(v0.x); q = h2f2(v0.y);
        a0.x += p.x; a0.y += p.y; a0.z += q.x; a0.w += q.y;
        p = h2f2(v1.x); q = h2f2(v1.y);
        a1.x += p.x; a1.y += p.y; a1.z += q.x; a1.w += q.y;
        p = h2f2(v2.x); q = h2f2(v2.y);
        a0.x += p.x; a0.y += p.y; a0.z += q.x; a0.w += q.y;
        p = h2f2(v3.x); q = h2f2(v3.y);
        a1.x += p.x; a1.y += p.y; a1.z += q.x; a1.w += q.y;
    }
    for (; j < end; ++j) {
        int s = ntl_i(&esrc[j]);
        uint2 v = T[(size_t)s * 4 + f4];
        float2 p = h2f2(v.x), q = h2f2(v.y);
        a0.x += p.x; a0.y += p.y; a0.z += q.x; a0.w += q.y;
    }
    if (active) {
        float* row = &sacc[g * 17 + f4 * 4];
        row[0] = dn * (a0.x + a1.x);
        row[1] = dn * (a0.y + a1.y);
        row[2] = dn * (a0.z + a1.z);
        row[3] = dn * (a0.w + a1.w);
    }
    __syncthreads();

    // epilogue: threads 0..63, one node each: 16x20 matmul + log_softmax
    if (t < 64) {
        int node = blockIdx.x * 64 + t;
        if (node < N) {
            float a[HDIM];
            float* row = &sacc[t * 17];
#pragma unroll
            for (int k = 0; k < HDIM; ++k) a[k] = row[k];
            float o[CDIM];
#pragma unroll
            for (int jj = 0; jj < CDIM; ++jj) o[jj] = b2s[jj];
#pragma unroll
            for (int k = 0; k < HDIM; ++k) {
                float ak = a[k];
#pragma unroll
                for (int jj = 0; jj < CDIM; ++jj) o[jj] += ak * W2s[k * CDIM + jj];
            }
            float m = o[0];
#pragma unroll
            for (int jj = 1; jj < CDIM; ++jj) m = fmaxf(m, o[jj]);
            float s = 0.f;
#pragma unroll
            for (int jj = 0; jj < CDIM; ++jj) s += __expf(o[jj] - m);
            float l = m + __logf(s);
            float4* out4 = reinterpret_cast<float4*>(out + (size_t)node * CDIM);
#pragma unroll
            for (int c = 0; c < CDIM / 4; ++c)
                nts_f4(&out4[c],
                       make_float4(o[4 * c + 0] - l, o[4 * c + 1] - l,
                                   o[4 * c + 2] - l, o[4 * c + 3] - l));
        }
    }
}

// ---------------- launch ----------------

extern "C" void kernel_launch(void* const* d_in, const int* in_sizes, int n_in,
                              void* d_out, int out_size, void* d_ws, size_t ws_size,
                              hipStream_t stream) {
    const float* x  = (const float*)d_in[0];
    const int* edge = (const int*)d_in[1];   // [2, E] int32
    const float* W1 = (const float*)d_in[2];
    const float* b1 = (const float*)d_in[3];
    const float* W2 = (const float*)d_in[4];
    const float* b2 = (const float*)d_in[5];
    float* out = (float*)d_out;

    const int N = in_sizes[0] / NDIM;   // 500000
    const int E = in_sizes[1] / 2;      // 8000000
    const int* src = edge;
    const int* dst = edge + E;

    const int tb = 256;
    const int nbN = (N + tb - 1) / tb;
    const int NB2 = (N + BMASK2) >> BSH2;       // 489 coarse buckets

    char* ws = (char*)d_ws;
    size_t off = 0;
    int*      deg    = (int*)(ws + off);    off += (size_t)N * 4;
    int*      cursor = (int*)(ws + off);    off += (size_t)N * 4;
    float*    dinv   = (float*)(ws + off);  off += (size_t)N * 4;
    __half*   xw1h   = (__half*)(ws + off); off += (size_t)N * HDIM * 2;
    __half*   hsh    = (__half*)(ws + off); off += (size_t)N * HDIM * 2;
    unsigned* tmp    = (unsigned*)(ws + off); off += (size_t)E * 4;
    int*      esrc   = (int*)(ws + off);    off += (size_t)E * 4;
    int*      bcnt   = (int*)(ws + off);    off += (size_t)NB2MAX * 4;
    int*      gcur   = (int*)(ws + off);    off += (size_t)NB2MAX * 4;

    // ---- CSR build ----
    hipMemsetAsync(bcnt, 0, (size_t)NB2 * 4, stream);
    histA<<<(E + 8191) / 8192, tb, 0, stream>>>(dst, bcnt, E, NB2);
    scan_k2<<<1, tb, 0, stream>>>(bcnt, gcur, NB2);   // bcnt -> B0, seeds gcur
    scatter_sort<<<(E + CH2 - 1) / CH2, tb, 0, stream>>>(src, dst, gcur, tmp, E, NB2);
    binC<<<NB2, tb, 0, stream>>>(tmp, bcnt, deg, cursor, esrc, N, E, NB2);

    dinv_kernel<<<nbN, tb, 0, stream>>>(deg, dinv, N);

    // dense matmul xw1h = fp16(dinv * (x @ W1))
    xw1_kernel<<<(N + 63) / 64, tb, 0, stream>>>(x, W1, dinv, xw1h, N);

    // layer 1: gather-reduce -> hsh = fp16(dinv * relu(...))
    gather1<<<(N + 63) / 64, tb, 0, stream>>>(esrc, cursor, deg, dinv, xw1h, b1, hsh, N);

    // layer 2: gather-reduce + fused W2 matmul + log_softmax -> out
    gather2<<<(N + 63) / 64, tb, 0, stream>>>(esrc, cursor, deg, dinv, hsh, W2, b2, out, N);
}

// Round 8
// 700.642 us; speedup vs baseline: 2.6195x; 1.2365x over previous
//
#include <hip/hip_runtime.h>
#include <hip/hip_bf16.h>
#include <hip/hip_fp16.h>

#define NDIM 100
#define HDIM 16
#define CDIM 20

#define BSH2   10                 // 1024 nodes per bucket
#define BMASK2 ((1 << BSH2) - 1)
#define NB2MAX 768                // supports N <= 786432
#define CH2    16384              // edges per scatter_sort block
#define LBUF_CAP 18432            // binC LDS staging capacity

// fp16 pack/unpack helpers (tables stored fp16, accumulation fp32)
__device__ inline float2 h2f2(unsigned u) {
    __half2 h = *reinterpret_cast<__half2*>(&u);
    return __half22float2(h);
}
__device__ inline unsigned f2h2(float a, float b) {
    __half2 h = __floats2half2_rn(a, b);
    return *reinterpret_cast<unsigned*>(&h);
}

// ---------------- pass A: bucket histogram -> bcnt[b] ----------------

__global__ __launch_bounds__(256) void histA(const int* __restrict__ dst,
                                             int* __restrict__ bcnt,
                                             int E, int NB2) {
    __shared__ int lh[NB2MAX];
    for (int t = threadIdx.x; t < NB2MAX; t += 256) lh[t] = 0;
    __syncthreads();

    int base = blockIdx.x * 8192;
    int endv = min(base + 8192, E);
    for (int e = base + threadIdx.x; e < endv; e += 256)
        atomicAdd(&lh[dst[e] >> BSH2], 1);
    __syncthreads();

    for (int t = threadIdx.x; t < NB2; t += 256) {
        int v = lh[t];
        if (v) atomicAdd(&bcnt[t], v);
    }
}

// ---- exclusive scan of bcnt in place (nb <= 2048), 1 block; also seeds gcur ----

__global__ __launch_bounds__(256) void scan_k2(int* __restrict__ bsum,
                                               int* __restrict__ gcur, int nb) {
    __shared__ int part[256];
    int t = threadIdx.x;
    int base = t * 8;
    int loc[8];
    int s = 0;
#pragma unroll
    for (int k = 0; k < 8; ++k) {
        int idx = base + k;
        loc[k] = (idx < nb) ? bsum[idx] : 0;
        s += loc[k];
    }
    part[t] = s;
    __syncthreads();
    for (int off = 1; off < 256; off <<= 1) {
        int add = (t >= off) ? part[t - off] : 0;
        __syncthreads();
        part[t] += add;
        __syncthreads();
    }
    int run = (t > 0) ? part[t - 1] : 0;
#pragma unroll
    for (int k = 0; k < 8; ++k) {
        int idx = base + k;
        if (idx < nb) { bsum[idx] = run; gcur[idx] = run; }
        run += loc[k];
    }
}

// ---------------- pass B: block-local counting sort in LDS + full-line copy-out ----
// 1024 threads/block: same grid (E/CH2), 4x wave parallelism per phase.

__global__ __launch_bounds__(1024) void scatter_sort(const int* __restrict__ src,
                                                     const int* __restrict__ dst,
                                                     int* __restrict__ gcur,
                                                     unsigned* __restrict__ tmp,
                                                     int E, int NB2) {
    __shared__ unsigned lbuf[CH2];   // 64 KB
    __shared__ int lcnt[1024];       // counts -> cursors
    __shared__ int lst[1024];        // local exclusive starts
    __shared__ int gb[1024];         // global run bases
    const int t = threadIdx.x;

    lcnt[t] = 0;
    __syncthreads();

    int base = blockIdx.x * CH2;
    int endv = min(base + CH2, E);
    for (int e = base + t; e < endv; e += 1024)
        atomicAdd(&lcnt[dst[e] >> BSH2], 1);
    __syncthreads();

    // inclusive scan of counts (1 per thread) in lst; keep counts in lcnt
    int c = lcnt[t];
    lst[t] = c;
    __syncthreads();
    for (int off = 1; off < 1024; off <<= 1) {
        int add = (t >= off) ? lst[t - off] : 0;
        __syncthreads();
        lst[t] += add;
        __syncthreads();
    }
    int ex = lst[t] - c;   // exclusive prefix

    // allocate one contiguous global run per bucket
    int gbase = 0;
    if (t < NB2 && c > 0) gbase = atomicAdd(&gcur[t], c);
    gb[t]   = gbase;
    lst[t]  = ex;          // local start
    lcnt[t] = ex;          // local cursor
    __syncthreads();

    // scatter into LDS, sorted by bucket
    for (int e = base + t; e < endv; e += 1024) {
        int d = dst[e];
        int b = d >> BSH2;
        int pos = atomicAdd(&lcnt[b], 1);
        lbuf[pos] = ((unsigned)src[e] << BSH2) | (unsigned)(d & BMASK2);
    }
    __syncthreads();

    // copy-out: 64 groups of 16 lanes, buckets round-robin (runs ~33 entries)
    int grp = t >> 4, lane = t & 15;
    for (int b = grp; b < NB2; b += 64) {
        int s0 = lst[b], g0 = gb[b];
        int len = lcnt[b] - s0;
        for (int k = lane; k < len; k += 16)
            tmp[(size_t)g0 + k] = lbuf[s0 + k];
    }
}

// ---------------- pass C: one block per bucket -> seg(end,deg), dinv, esrc ----------------
// 1024 threads: 1 node per thread for hist/scan; lbuf staging keeps esrc writes full-line.

__global__ __launch_bounds__(1024) void binC(const unsigned* __restrict__ tmp,
                                             const int* __restrict__ B0,
                                             int2* __restrict__ seg,
                                             float* __restrict__ dinv,
                                             int* __restrict__ esrc,
                                             int N, int E, int NB2) {
    __shared__ int lbuf[LBUF_CAP];   // 72 KB
    __shared__ int lh[1024];
    __shared__ int lcur[1024];
    int b = blockIdx.x, t = threadIdx.x;

    lh[t] = 0;
    __syncthreads();

    int lo = B0[b];
    int hi = (b + 1 < NB2) ? B0[b + 1] : E;

    // per-node histogram (= in-degree)
    for (int i = lo + t; i < hi; i += 1024)
        atomicAdd(&lh[tmp[i] & BMASK2], 1);
    __syncthreads();

    int cnt = lh[t];
    __syncthreads();
    // inclusive scan of lh (1 per thread)
    for (int off = 1; off < 1024; off <<= 1) {
        int add = (t >= off) ? lh[t - off] : 0;
        __syncthreads();
        lh[t] += add;
        __syncthreads();
    }
    int end   = lo + lh[t];
    int start = end - cnt;

    int node = (b << BSH2) + t;
    if (node < N) {
        seg[node]  = make_int2(end, cnt);
        dinv[node] = rsqrtf((float)(cnt + 1));   // +1 = self-loop
    }
    lcur[t] = start - lo;   // local cursor for staging
    __syncthreads();

    bool fits = (hi - lo) <= LBUF_CAP;
    if (fits) {
        for (int i = lo + t; i < hi; i += 1024) {
            unsigned v = tmp[i];
            int pos = atomicAdd(&lcur[v & BMASK2], 1);
            lbuf[pos] = (int)(v >> BSH2);
        }
        __syncthreads();
        for (int i = lo + t; i < hi; i += 1024)
            esrc[i] = lbuf[i - lo];
    } else {
        for (int i = lo + t; i < hi; i += 1024) {
            unsigned v = tmp[i];
            int pos = atomicAdd(&lcur[v & BMASK2], 1);
            esrc[(size_t)lo + pos] = (int)(v >> BSH2);
        }
    }
}

// ---------------- xw1h = fp16( dinv[n] * (x @ W1) )  ([N,100] @ [100,16]) ----------------

__global__ __launch_bounds__(256) void xw1_kernel(const float* __restrict__ x,
                                                  const float* __restrict__ W1,
                                                  const float* __restrict__ dinv,
                                                  __half* __restrict__ xw1h, int N) {
    __shared__ float Ws[NDIM * HDIM];  // [k][j]
    for (int t = threadIdx.x; t < NDIM * HDIM; t += 256) Ws[t] = W1[t];
    __syncthreads();

    const int ln = threadIdx.x >> 2;
    const int q  = threadIdx.x & 3;
    const int node = blockIdx.x * 64 + ln;
    if (node >= N) return;

    const float4* xr  = reinterpret_cast<const float4*>(x + (size_t)node * NDIM);
    const float4* Ws4 = reinterpret_cast<const float4*>(Ws);

    float4 acc = make_float4(0.f, 0.f, 0.f, 0.f);
#pragma unroll
    for (int kk = 0; kk < NDIM / 4; ++kk) {
        float4 xv = xr[kk];
        float xs[4] = {xv.x, xv.y, xv.z, xv.w};
#pragma unroll
        for (int c = 0; c < 4; ++c) {
            float4 w = Ws4[(kk * 4 + c) * 4 + q];
            acc.x += xs[c] * w.x;
            acc.y += xs[c] * w.y;
            acc.z += xs[c] * w.z;
            acc.w += xs[c] * w.w;
        }
    }
    float dn = dinv[node];
    uint2 o;
    o.x = f2h2(dn * acc.x, dn * acc.y);
    o.y = f2h2(dn * acc.z, dn * acc.w);
    reinterpret_cast<uint2*>(xw1h)[(size_t)node * 4 + q] = o;
}

// ---------------- layer-1 gather: hsh = fp16(dinv * relu(dn*(sum + self) + b1)) ----
// 4 lanes per node, 8B (half4) per lane; 64 nodes per 256-thread block.

__global__ __launch_bounds__(256) void gather1(const int* __restrict__ esrc,
                                               const int2* __restrict__ seg,
                                               const float* __restrict__ dinv,
                                               const __half* __restrict__ xw1h,
                                               const float* __restrict__ b1,
                                               __half* __restrict__ hsh, int N) {
    int g  = threadIdx.x >> 2;
    int f4 = threadIdx.x & 3;
    int n  = blockIdx.x * 64 + g;
    if (n >= N) return;

    int2 cd   = seg[n];
    int end   = cd.x;
    int start = end - cd.y;
    float dn  = dinv[n];

    const uint2* T = reinterpret_cast<const uint2*>(xw1h);
    uint2 sv = T[(size_t)n * 4 + f4];
    float2 s01 = h2f2(sv.x), s23 = h2f2(sv.y);
    float4 a0 = make_float4(s01.x, s01.y, s23.x, s23.y);  // self term
    float4 a1 = make_float4(0.f, 0.f, 0.f, 0.f);

    int j = start;
    for (; j + 3 < end; j += 4) {
        int i0 = esrc[j + 0], i1 = esrc[j + 1];
        int i2 = esrc[j + 2], i3 = esrc[j + 3];
        uint2 v0 = T[(size_t)i0 * 4 + f4];
        uint2 v1 = T[(size_t)i1 * 4 + f4];
        uint2 v2 = T[(size_t)i2 * 4 + f4];
        uint2 v3 = T[(size_t)i3 * 4 + f4];
        float2 p, q;
        p = h2f2(v0.x); q = h2f2(v0.y);
        a0.x += p.x; a0.y += p.y; a0.z += q.x; a0.w += q.y;
        p = h2f2(v1.x); q = h2f2(v1.y);
        a1.x += p.x; a1.y += p.y; a1.z += q.x; a1.w += q.y;
        p = h2f2(v2.x); q = h2f2(v2.y);
        a0.x += p.x; a0.y += p.y; a0.z += q.x; a0.w += q.y;
        p = h2f2(v3.x); q = h2f2(v3.y);
        a1.x += p.x; a1.y += p.y; a1.z += q.x; a1.w += q.y;
    }
    for (; j < end; ++j) {
        int s = esrc[j];
        uint2 v = T[(size_t)s * 4 + f4];
        float2 p = h2f2(v.x), q = h2f2(v.y);
        a0.x += p.x; a0.y += p.y; a0.z += q.x; a0.w += q.y;
    }
    float4 acc = make_float4(a0.x + a1.x, a0.y + a1.y, a0.z + a1.z, a0.w + a1.w);
    float4 bv = reinterpret_cast<const float4*>(b1)[f4];
    float hx = dn * fmaxf(dn * acc.x + bv.x, 0.f);
    float hy = dn * fmaxf(dn * acc.y + bv.y, 0.f);
    float hz = dn * fmaxf(dn * acc.z + bv.z, 0.f);
    float hw = dn * fmaxf(dn * acc.w + bv.w, 0.f);
    uint2 o;
    o.x = f2h2(hx, hy);
    o.y = f2h2(hz, hw);
    reinterpret_cast<uint2*>(hsh)[(size_t)n * 4 + f4] = o;
}

// ---------------- layer-2 gather: agg2 = dn * (sum hsh[s] + hsh[n]) (fp32 out) ----

__global__ __launch_bounds__(256) void gather2(const int* __restrict__ esrc,
                                               const int2* __restrict__ seg,
                                               const float* __restrict__ dinv,
                                               const __half* __restrict__ hsh,
                                               float* __restrict__ agg2, int N) {
    int g  = threadIdx.x >> 2;
    int f4 = threadIdx.x & 3;
    int n  = blockIdx.x * 64 + g;
    if (n >= N) return;

    int2 cd   = seg[n];
    int end   = cd.x;
    int start = end - cd.y;
    float dn  = dinv[n];

    const uint2* T = reinterpret_cast<const uint2*>(hsh);
    uint2 sv = T[(size_t)n * 4 + f4];
    float2 s01 = h2f2(sv.x), s23 = h2f2(sv.y);
    float4 a0 = make_float4(s01.x, s01.y, s23.x, s23.y);  // self term
    float4 a1 = make_float4(0.f, 0.f, 0.f, 0.f);

    int j = start;
    for (; j + 3 < end; j += 4) {
        int i0 = esrc[j + 0], i1 = esrc[j + 1];
        int i2 = esrc[j + 2], i3 = esrc[j + 3];
        uint2 v0 = T[(size_t)i0 * 4 + f4];
        uint2 v1 = T[(size_t)i1 * 4 + f4];
        uint2 v2 = T[(size_t)i2 * 4 + f4];
        uint2 v3 = T[(size_t)i3 * 4 + f4];
        float2 p, q;
        p = h2f2(v0.x); q = h2f2(v0.y);
        a0.x += p.x; a0.y += p.y; a0.z += q.x; a0.w += q.y;
        p = h2f2(v1.x); q = h2f2(v1.y);
        a1.x += p.x; a1.y += p.y; a1.z += q.x; a1.w += q.y;
        p = h2f2(v2.x); q = h2f2(v2.y);
        a0.x += p.x; a0.y += p.y; a0.z += q.x; a0.w += q.y;
        p = h2f2(v3.x); q = h2f2(v3.y);
        a1.x += p.x; a1.y += p.y; a1.z += q.x; a1.w += q.y;
    }
    for (; j < end; ++j) {
        int s = esrc[j];
        uint2 v = T[(size_t)s * 4 + f4];
        float2 p = h2f2(v.x), q = h2f2(v.y);
        a0.x += p.x; a0.y += p.y; a0.z += q.x; a0.w += q.y;
    }
    float4 o;
    o.x = dn * (a0.x + a1.x);
    o.y = dn * (a0.y + a1.y);
    o.z = dn * (a0.z + a1.z);
    o.w = dn * (a0.w + a1.w);
    reinterpret_cast<float4*>(agg2)[(size_t)n * 4 + f4] = o;
}

// ---------------- final: out = log_softmax(agg2 @ W2 + b2) ----------------

__global__ __launch_bounds__(256) void final_kernel(const float* __restrict__ agg2,
                                                    const float* __restrict__ W2,
                                                    const float* __restrict__ b2,
                                                    float* __restrict__ out, int N) {
    __shared__ float W2t[CDIM * HDIM];  // [j][k]
    __shared__ float b2s[CDIM];
    for (int t = threadIdx.x; t < CDIM * HDIM; t += 256) {
        int j = t / HDIM, k = t % HDIM;
        W2t[t] = W2[k * CDIM + j];
    }
    for (int t = threadIdx.x; t < CDIM; t += 256) b2s[t] = b2[t];
    __syncthreads();

    int n = blockIdx.x * 256 + threadIdx.x;
    if (n >= N) return;

    float a[HDIM];
    const float4* a4 = reinterpret_cast<const float4*>(agg2 + (size_t)n * HDIM);
#pragma unroll
    for (int c = 0; c < HDIM / 4; ++c) {
        float4 v = a4[c];
        a[4 * c + 0] = v.x; a[4 * c + 1] = v.y;
        a[4 * c + 2] = v.z; a[4 * c + 3] = v.w;
    }
    float o[CDIM];
#pragma unroll
    for (int j = 0; j < CDIM; ++j) {
        const float4* w4 = reinterpret_cast<const float4*>(W2t + j * HDIM);
        float s = b2s[j];
#pragma unroll
        for (int c = 0; c < HDIM / 4; ++c) {
            float4 w = w4[c];
            s += a[4 * c + 0] * w.x + a[4 * c + 1] * w.y +
                 a[4 * c + 2] * w.z + a[4 * c + 3] * w.w;
        }
        o[j] = s;
    }
    float m = o[0];
#pragma unroll
    for (int j = 1; j < CDIM; ++j) m = fmaxf(m, o[j]);
    float s = 0.f;
#pragma unroll
    for (int j = 0; j < CDIM; ++j) s += __expf(o[j] - m);
    float l = __logf(s);
    float4* out4 = reinterpret_cast<float4*>(out + (size_t)n * CDIM);
#pragma unroll
    for (int c = 0; c < CDIM / 4; ++c)
        out4[c] = make_float4(o[4 * c + 0] - m - l, o[4 * c + 1] - m - l,
                              o[4 * c + 2] - m - l, o[4 * c + 3] - m - l);
}

// ---------------- launch ----------------

extern "C" void kernel_launch(void* const* d_in, const int* in_sizes, int n_in,
                              void* d_out, int out_size, void* d_ws, size_t ws_size,
                              hipStream_t stream) {
    const float* x  = (const float*)d_in[0];
    const int* edge = (const int*)d_in[1];   // [2, E] int32
    const float* W1 = (const float*)d_in[2];
    const float* b1 = (const float*)d_in[3];
    const float* W2 = (const float*)d_in[4];
    const float* b2 = (const float*)d_in[5];
    float* out = (float*)d_out;

    const int N = in_sizes[0] / NDIM;   // 500000
    const int E = in_sizes[1] / 2;      // 8000000
    const int* src = edge;
    const int* dst = edge + E;

    const int tb = 256;
    const int nbN = (N + tb - 1) / tb;
    const int NB2 = (N + BMASK2) >> BSH2;       // 489 coarse buckets

    char* ws = (char*)d_ws;
    size_t off = 0;
    int2*     seg    = (int2*)(ws + off);   off += (size_t)N * 8;
    float*    dinv   = (float*)(ws + off);  off += (size_t)N * 4;
    __half*   xw1h   = (__half*)(ws + off); off += (size_t)N * HDIM * 2;
    __half*   hsh    = (__half*)(ws + off); off += (size_t)N * HDIM * 2;
    float*    agg2   = (float*)(ws + off);  off += (size_t)N * HDIM * 4;
    int*      esrc   = (int*)(ws + off);    off += (size_t)E * 4;
    int*      bcnt   = (int*)(ws + off);    off += (size_t)NB2MAX * 4;
    int*      gcur   = (int*)(ws + off);    off += (size_t)NB2MAX * 4;

    // tmp (bucket-major packed edges, E*4 = 32MB) aliases agg2 (N*HDIM*4 = 32MB);
    // agg2 is only written by gather2, long after binC has consumed tmp.
    unsigned* tmp = (unsigned*)agg2;

    // ---- CSR build ----
    hipMemsetAsync(bcnt, 0, (size_t)NB2 * 4, stream);
    histA<<<(E + 8191) / 8192, tb, 0, stream>>>(dst, bcnt, E, NB2);
    scan_k2<<<1, tb, 0, stream>>>(bcnt, gcur, NB2);   // bcnt -> B0, seeds gcur
    scatter_sort<<<(E + CH2 - 1) / CH2, 1024, 0, stream>>>(src, dst, gcur, tmp, E, NB2);
    binC<<<NB2, 1024, 0, stream>>>(tmp, bcnt, seg, dinv, esrc, N, E, NB2);

    // dense matmul xw1h = fp16(dinv * (x @ W1))
    xw1_kernel<<<(N + 63) / 64, tb, 0, stream>>>(x, W1, dinv, xw1h, N);

    // layer 1: gather-reduce -> hsh = fp16(dinv * relu(...))
    gather1<<<(N + 63) / 64, tb, 0, stream>>>(esrc, seg, dinv, xw1h, b1, hsh, N);

    // layer 2: gather-reduce -> agg2 = dn * (sum hsh + self)
    gather2<<<(N + 63) / 64, tb, 0, stream>>>(esrc, seg, dinv, hsh, agg2, N);

    // fused projection + log_softmax -> out
    final_kernel<<<nbN, tb, 0, stream>>>(agg2, W2, b2, out, N);
}